// Round 8
// baseline (174.457 us; speedup 1.0000x reference)
//
#include <hip/hip_runtime.h>

// Problem constants
#define NB 2
#define CC 512
#define NN 2304
#define NH 8
#define DD 16
#define TT 128          // NH*DD
#define O3 384          // 3*TT

typedef __attribute__((ext_vector_type(4))) float f32x4;
typedef __attribute__((ext_vector_type(8))) __bf16 bf16x8;
typedef __attribute__((ext_vector_type(4))) __bf16 bf16x4;
typedef __attribute__((ext_vector_type(4))) _Float16 f16x4;
typedef __attribute__((ext_vector_type(2))) __fp16 hf16x2;   // cvt_pkrtz return type

union hf2pair {                       // bit-reinterpret 2x(__fp16 x2) -> f16x4
    hf16x2 h[2];
    f16x4  v;
};

// workspace layout (bytes)
#define OFF_WQ 0u               // 384*512*2    =   393,216
#define OFF_WO 393216u          // 512*128*2    =   131,072
#define OFF_Q  524288u          // 2*8*2304*16*2 = 1,179,648
#define OFF_K  1703936u
#define OFF_VT 2883584u
#define OFF_AO 4063232u         // 2*2304*128*2 = 1,179,648 -> 5,242,880

// ---------------------------------------------------------------------------
// Kernel 0w: weights-only fp32 -> bf16 (tiny; x-transpose moved into k1).
// ---------------------------------------------------------------------------
__global__ __launch_bounds__(256) void k0w(
    const float* __restrict__ wqkv, const float* __restrict__ wout,
    __bf16* __restrict__ wqb, __bf16* __restrict__ wob)
{
    int base = blockIdx.x * 4096 + threadIdx.x;
#pragma unroll
    for (int i = 0; i < 16; i++) {
        int j = base + i * 256;             // 64 blocks cover 262,144 elements
        if (j < O3 * CC) wqb[j] = (__bf16)wqkv[j];
        else             wob[j - O3 * CC] = (__bf16)wout[j - O3 * CC];
    }
}

// ---------------------------------------------------------------------------
// Kernel 1: QKV GEMM + fused L2 norm, x-transpose fused via LDS.
// R8: ob COLLAPSED (R7's fatal flaw was 6x duplicated staging). Grid (36,2) =
// 72 blocks x 512 thr. Each block stages x[b][:][n0..n0+63] -> As[64][520]
// bf16 ONCE (coalesced f32x4 along n), then 8 waves = 4 n-subtiles x 2
// o-groups compute all 384 output channels (12 MFMA tiles/wave) with the
// verified bf16 b128 load path (W from k0w's bf16 copy — no per-ks cvt).
// Outputs: Q,K: [bh][n][16] f16 ;  VT: [bh][16][n] f16
// ---------------------------------------------------------------------------
__global__ __launch_bounds__(512) void k1_qkv(
    const float* __restrict__ x, const __bf16* __restrict__ wqb,
    _Float16* __restrict__ Q, _Float16* __restrict__ K, _Float16* __restrict__ VT)
{
    __shared__ __bf16 As[64][520];     // 66,560 B; row stride 1040B = 65*16B
    int nt = blockIdx.x, b = blockIdx.y;
    int tid = threadIdx.x;
    int lane = tid & 63, wave = tid >> 6;
    int quad = lane >> 4, col = lane & 15;
    int n0 = nt * 64;

    // ---- stage x[b][c][n0..n0+63] -> As[n][c] (bf16, transposed), once ----
    {
        int nq = (tid & 15) * 4;       // 0,4,..,60
        int cs = tid >> 4;             // 0..31
#pragma unroll
        for (int it = 0; it < 16; ++it) {
            int c = it * 32 + cs;
            f32x4 v = *(const f32x4*)(x + ((size_t)b * CC + c) * NN + n0 + nq);
            As[nq + 0][c] = (__bf16)v[0];
            As[nq + 1][c] = (__bf16)v[1];
            As[nq + 2][c] = (__bf16)v[2];
            As[nq + 3][c] = (__bf16)v[3];
        }
    }
    __syncthreads();

    int ng = wave & 3;                 // n sub-tile (16 rows)
    int og = wave >> 2;                // o-group: 0 -> tiles 0..11, 1 -> 12..23
    int nrow = ng * 16 + col;

    f32x4 acc[12];
#pragma unroll
    for (int s = 0; s < 12; s++) acc[s] = (f32x4){0.f, 0.f, 0.f, 0.f};

    const __bf16* wbase = wqb + (size_t)(og * 192 + col) * CC + quad * 8;

#pragma unroll
    for (int ks = 0; ks < 16; ks++) {
        bf16x8 a = *(const bf16x8*)(&As[nrow][quad * 8 + ks * 32]);
#pragma unroll
        for (int s = 0; s < 12; s++) {
            bf16x8 w = *(const bf16x8*)(wbase + (size_t)(s * 16) * CC + ks * 32);
            acc[s] = __builtin_amdgcn_mfma_f32_16x16x32_bf16(a, w, acc[s], 0, 0, 0);
        }
    }

#pragma unroll
    for (int s = 0; s < 12; s++) {
        int oc = og * 192 + s * 16 + col;
        int d = oc & 15, h = (oc >> 4) & 7, kind = oc >> 7;  // 0=q 1=k 2=v
        f32x4 v = acc[s];
        if (kind < 2) {
            float ss0 = v[0] * v[0], ss1 = v[1] * v[1], ss2 = v[2] * v[2], ss3 = v[3] * v[3];
#pragma unroll
            for (int m = 1; m < 16; m <<= 1) {
                ss0 += __shfl_xor(ss0, m);
                ss1 += __shfl_xor(ss1, m);
                ss2 += __shfl_xor(ss2, m);
                ss3 += __shfl_xor(ss3, m);
            }
            v[0] *= 1.0f / fmaxf(sqrtf(ss0), 1e-12f);
            v[1] *= 1.0f / fmaxf(sqrtf(ss1), 1e-12f);
            v[2] *= 1.0f / fmaxf(sqrtf(ss2), 1e-12f);
            v[3] *= 1.0f / fmaxf(sqrtf(ss3), 1e-12f);
            _Float16* dst = (kind == 0 ? Q : K) + (size_t)(b * NH + h) * NN * DD;
#pragma unroll
            for (int r = 0; r < 4; r++) {
                int n = n0 + ng * 16 + quad * 4 + r;
                dst[(size_t)n * DD + d] = (_Float16)v[r];
            }
        } else {
            f16x4 pk;
#pragma unroll
            for (int r = 0; r < 4; r++) pk[r] = (_Float16)v[r];
            int n = n0 + ng * 16 + quad * 4;
            *(f16x4*)(VT + (size_t)((b * NH + h) * DD + d) * NN + n) = pk;
        }
    }
}

// ---------------------------------------------------------------------------
// Kernel 2: attention — transpose-free flash, 8 waves x 288 keys, LDS combine.
// (Byte-identical to verified R6.) temperature*log2e folded into Q frags;
// packed v_cvt_pkrtz for P f32->f16; l-sum via ones-A-fragment MFMA.
// Output: AO[b][n][t=h*16+d] bf16.
// ---------------------------------------------------------------------------
__global__ __launch_bounds__(512) void k2_attn(
    const _Float16* __restrict__ Q, const _Float16* __restrict__ K,
    const _Float16* __restrict__ VT, const float* __restrict__ temp,
    __bf16* __restrict__ AO)
{
    __shared__ float Osh[8][16][64];   // [wave][d][q]
    __shared__ float Lsh[8][64];       // [wave][q]

    int qt = blockIdx.x, bh = blockIdx.y;
    int lane = threadIdx.x & 63, wave = threadIdx.x >> 6;
    int quad = lane >> 4, col = lane & 15;
    int kbase = wave * 288;               // 8 waves x 288 keys = full 2304
    int qbase = qt * 64;

    const _Float16* Qb = Q + (size_t)bh * NN * DD;
    float tl2 = temp[bh & 7] * 1.4426950408889634f;   // exp(x)=2^(x*log2e)
    _Float16 tl2h = (_Float16)tl2;

    f16x4 qf0 = *(const f16x4*)(Qb + (size_t)(qbase +  0 + col) * DD + quad * 4);
    f16x4 qf1 = *(const f16x4*)(Qb + (size_t)(qbase + 16 + col) * DD + quad * 4);
    f16x4 qf2 = *(const f16x4*)(Qb + (size_t)(qbase + 32 + col) * DD + quad * 4);
    f16x4 qf3 = *(const f16x4*)(Qb + (size_t)(qbase + 48 + col) * DD + quad * 4);
#pragma unroll
    for (int j = 0; j < 4; j++) {      // fold temperature*log2e into Q
        qf0[j] *= tl2h; qf1[j] *= tl2h; qf2[j] *= tl2h; qf3[j] *= tl2h;
    }
    const f16x4 onesf = {(_Float16)1.f, (_Float16)1.f, (_Float16)1.f, (_Float16)1.f};

    f32x4 oa0 = {0.f,0.f,0.f,0.f}, oa1 = {0.f,0.f,0.f,0.f};
    f32x4 oa2 = {0.f,0.f,0.f,0.f}, oa3 = {0.f,0.f,0.f,0.f};
    f32x4 lc0 = {0.f,0.f,0.f,0.f}, lc1 = {0.f,0.f,0.f,0.f};
    f32x4 lc2 = {0.f,0.f,0.f,0.f}, lc3 = {0.f,0.f,0.f,0.f};
    const f32x4 zc = {0.f,0.f,0.f,0.f};

    const _Float16* kp = K + (size_t)bh * NN * DD + (size_t)(kbase + col) * DD + quad * 4;
    const _Float16* vp = VT + (size_t)bh * DD * NN + (size_t)col * NN + kbase + quad * 4;

    f16x4 kfa = *(const f16x4*)(kp);
    f16x4 kfb = *(const f16x4*)(kp + 16 * DD);
    f16x4 vfa = *(const f16x4*)(vp);
    f16x4 vfb = *(const f16x4*)(vp + 16);

#define K2_CHUNK(KF, VF)                                                        \
    {                                                                           \
        f32x4 s0 = __builtin_amdgcn_mfma_f32_16x16x16f16(KF, qf0, zc, 0, 0, 0); \
        f32x4 s1 = __builtin_amdgcn_mfma_f32_16x16x16f16(KF, qf1, zc, 0, 0, 0); \
        f32x4 s2 = __builtin_amdgcn_mfma_f32_16x16x16f16(KF, qf2, zc, 0, 0, 0); \
        f32x4 s3 = __builtin_amdgcn_mfma_f32_16x16x16f16(KF, qf3, zc, 0, 0, 0); \
        hf2pair u0, u1, u2, u3;                                                 \
        u0.h[0] = __builtin_amdgcn_cvt_pkrtz(__builtin_amdgcn_exp2f(s0[0]),     \
                                             __builtin_amdgcn_exp2f(s0[1]));    \
        u0.h[1] = __builtin_amdgcn_cvt_pkrtz(__builtin_amdgcn_exp2f(s0[2]),     \
                                             __builtin_amdgcn_exp2f(s0[3]));    \
        u1.h[0] = __builtin_amdgcn_cvt_pkrtz(__builtin_amdgcn_exp2f(s1[0]),     \
                                             __builtin_amdgcn_exp2f(s1[1]));    \
        u1.h[1] = __builtin_amdgcn_cvt_pkrtz(__builtin_amdgcn_exp2f(s1[2]),     \
                                             __builtin_amdgcn_exp2f(s1[3]));    \
        u2.h[0] = __builtin_amdgcn_cvt_pkrtz(__builtin_amdgcn_exp2f(s2[0]),     \
                                             __builtin_amdgcn_exp2f(s2[1]));    \
        u2.h[1] = __builtin_amdgcn_cvt_pkrtz(__builtin_amdgcn_exp2f(s2[2]),     \
                                             __builtin_amdgcn_exp2f(s2[3]));    \
        u3.h[0] = __builtin_amdgcn_cvt_pkrtz(__builtin_amdgcn_exp2f(s3[0]),     \
                                             __builtin_amdgcn_exp2f(s3[1]));    \
        u3.h[1] = __builtin_amdgcn_cvt_pkrtz(__builtin_amdgcn_exp2f(s3[2]),     \
                                             __builtin_amdgcn_exp2f(s3[3]));    \
        f16x4 p0 = u0.v, p1 = u1.v, p2 = u2.v, p3 = u3.v;                       \
        lc0 = __builtin_amdgcn_mfma_f32_16x16x16f16(onesf, p0, lc0, 0, 0, 0);   \
        lc1 = __builtin_amdgcn_mfma_f32_16x16x16f16(onesf, p1, lc1, 0, 0, 0);   \
        lc2 = __builtin_amdgcn_mfma_f32_16x16x16f16(onesf, p2, lc2, 0, 0, 0);   \
        lc3 = __builtin_amdgcn_mfma_f32_16x16x16f16(onesf, p3, lc3, 0, 0, 0);   \
        oa0 = __builtin_amdgcn_mfma_f32_16x16x16f16(VF, p0, oa0, 0, 0, 0);      \
        oa1 = __builtin_amdgcn_mfma_f32_16x16x16f16(VF, p1, oa1, 0, 0, 0);      \
        oa2 = __builtin_amdgcn_mfma_f32_16x16x16f16(VF, p2, oa2, 0, 0, 0);      \
        oa3 = __builtin_amdgcn_mfma_f32_16x16x16f16(VF, p3, oa3, 0, 0, 0);      \
    }

    for (int g = 0; g < 9; ++g) {        // 9 groups x 32 keys = 288
        f16x4 kna, knb, vna, vnb;
        if (g < 8) {
            kna = *(const f16x4*)(kp + 32 * DD);
            knb = *(const f16x4*)(kp + 48 * DD);
            vna = *(const f16x4*)(vp + 32);
            vnb = *(const f16x4*)(vp + 48);
        }
        K2_CHUNK(kfa, vfa)
        K2_CHUNK(kfb, vfb)
        kfa = kna; kfb = knb; vfa = vna; vfb = vnb;
        kp += 32 * DD; vp += 32;
    }
#undef K2_CHUNK

    // lc rows are all identical = l[q=col] partial over this wave's keys.
#pragma unroll
    for (int r = 0; r < 4; ++r) {
        Osh[wave][quad * 4 + r][ 0 + col] = oa0[r];
        Osh[wave][quad * 4 + r][16 + col] = oa1[r];
        Osh[wave][quad * 4 + r][32 + col] = oa2[r];
        Osh[wave][quad * 4 + r][48 + col] = oa3[r];
    }
    float lv = (quad == 0) ? lc0[0] : (quad == 1) ? lc1[0] : (quad == 2) ? lc2[0] : lc3[0];
    Lsh[wave][quad * 16 + col] = lv;
    __syncthreads();

    int t = threadIdx.x;
    int q = t & 63, dg = t >> 6;          // dg in 0..7 -> d = dg*2, dg*2+1
    float l = 0.f;
#pragma unroll
    for (int w = 0; w < 8; ++w) l += Lsh[w][q];
    float inv = 1.0f / l;
    float o0 = 0.f, o1 = 0.f;
#pragma unroll
    for (int w = 0; w < 8; ++w) {
        o0 += Osh[w][dg * 2 + 0][q];
        o1 += Osh[w][dg * 2 + 1][q];
    }
    int b = bh >> 3, h = bh & 7;
    __bf16* dst = AO + (size_t)(b * NN + qbase + q) * TT + h * DD + dg * 2;
    dst[0] = (__bf16)(o0 * inv);
    dst[1] = (__bf16)(o1 * inv);
}

// ---------------------------------------------------------------------------
// Kernel 3: projection  out[b,c,n] = sum_t w_out[c,t] * AO[b,n,t]  (pre-BN fp32
// straight into d_out). c-slab 32 per wave: grid (16,36,2)=1152 blocks.
// (Byte-identical to verified R6.)
// ---------------------------------------------------------------------------
__global__ __launch_bounds__(256) void k3_proj(
    const __bf16* __restrict__ AO, const __bf16* __restrict__ wob,
    float* __restrict__ out)
{
    int cb = blockIdx.x, nt = blockIdx.y, b = blockIdx.z;
    int lane = threadIdx.x & 63, wave = threadIdx.x >> 6;
    int quad = lane >> 4, col = lane & 15;
    int n0 = nt * 64 + wave * 16, c0 = cb * 32;

    f32x4 acc0 = {0.f, 0.f, 0.f, 0.f};
    f32x4 acc1 = {0.f, 0.f, 0.f, 0.f};

    const __bf16* ab = AO + (size_t)(b * NN + n0 + col) * TT + quad * 8;
    const __bf16* wb0 = wob + (size_t)(c0 + col) * TT + quad * 8;
    const __bf16* wb1 = wb0 + 16 * TT;
#pragma unroll
    for (int ks = 0; ks < 4; ks++) {
        bf16x8 a  = *(const bf16x8*)(ab + ks * 32);
        bf16x8 w0 = *(const bf16x8*)(wb0 + ks * 32);
        bf16x8 w1 = *(const bf16x8*)(wb1 + ks * 32);
        acc0 = __builtin_amdgcn_mfma_f32_16x16x32_bf16(a, w0, acc0, 0, 0, 0);
        acc1 = __builtin_amdgcn_mfma_f32_16x16x32_bf16(a, w1, acc1, 0, 0, 0);
    }
#pragma unroll
    for (int s = 0; s < 2; s++) {
        int c = c0 + s * 16 + col;
        float* dst = out + (size_t)(b * CC + c) * NN + n0 + quad * 4;
        *(f32x4*)dst = (s == 0) ? acc0 : acc1;
    }
}

// ---------------------------------------------------------------------------
// Kernel 4: training-mode BatchNorm, in place on d_out. One block per channel.
// (Byte-identical to verified R6.)
// ---------------------------------------------------------------------------
__global__ __launch_bounds__(256) void k4_bn(
    float* __restrict__ out, const float* __restrict__ gamma,
    const float* __restrict__ beta)
{
    int c = blockIdx.x;
    int t = threadIdx.x;
    float vals[18];
    float s = 0.f, q = 0.f;
#pragma unroll
    for (int i = 0; i < 18; i++) {
        int j = i * 256 + t;          // 0..4607 over (b,n)
        int b = j / NN, n = j % NN;
        float v = out[(size_t)(b * CC + c) * NN + n];
        vals[i] = v; s += v; q += v * v;
    }
#pragma unroll
    for (int m = 1; m < 64; m <<= 1) { s += __shfl_xor(s, m); q += __shfl_xor(q, m); }
    __shared__ float rs[4], rq[4];
    int lane = t & 63, wave = t >> 6;
    if (lane == 0) { rs[wave] = s; rq[wave] = q; }
    __syncthreads();
    s = rs[0] + rs[1] + rs[2] + rs[3];
    q = rq[0] + rq[1] + rq[2] + rq[3];
    float mean = s * (1.0f / 4608.0f);
    float var = q * (1.0f / 4608.0f) - mean * mean;
    float sc = rsqrtf(var + 1e-5f) * gamma[c];
    float sh = beta[c] - mean * sc;
#pragma unroll
    for (int i = 0; i < 18; i++) {
        int j = i * 256 + t;
        int b = j / NN, n = j % NN;
        out[(size_t)(b * CC + c) * NN + n] = vals[i] * sc + sh;
    }
}

// ---------------------------------------------------------------------------
extern "C" void kernel_launch(void* const* d_in, const int* in_sizes, int n_in,
                              void* d_out, int out_size, void* d_ws, size_t ws_size,
                              hipStream_t stream) {
    const float* x     = (const float*)d_in[0];
    const float* wqkv  = (const float*)d_in[1];
    const float* temp  = (const float*)d_in[2];
    const float* wout  = (const float*)d_in[3];
    const float* gamma = (const float*)d_in[4];
    const float* beta  = (const float*)d_in[5];
    float* out = (float*)d_out;
    char* ws = (char*)d_ws;

    __bf16*   wqb = (__bf16*)(ws + OFF_WQ);
    __bf16*   wob = (__bf16*)(ws + OFF_WO);
    _Float16* Q   = (_Float16*)(ws + OFF_Q);
    _Float16* K   = (_Float16*)(ws + OFF_K);
    _Float16* VT  = (_Float16*)(ws + OFF_VT);
    __bf16*   AO  = (__bf16*)(ws + OFF_AO);

    k0w<<<64, 256, 0, stream>>>(wqkv, wout, wqb, wob);
    k1_qkv<<<dim3(36, 2), 512, 0, stream>>>(x, wqb, Q, K, VT);
    k2_attn<<<dim3(36, 16), 512, 0, stream>>>(Q, K, VT, temp, AO);
    k3_proj<<<dim3(16, 36, 2), 256, 0, stream>>>(AO, wob, out);
    k4_bn<<<512, 256, 0, stream>>>(out, gamma, beta);
}

// Round 9
// 131.470 us; speedup vs baseline: 1.3270x; 1.3270x over previous
//
#include <hip/hip_runtime.h>

// Problem constants
#define NB 2
#define CC 512
#define NN 2304
#define NH 8
#define DD 16
#define TT 128          // NH*DD
#define O3 384          // 3*TT

typedef __attribute__((ext_vector_type(4))) float f32x4;
typedef __attribute__((ext_vector_type(8))) __bf16 bf16x8;
typedef __attribute__((ext_vector_type(4))) __bf16 bf16x4;
typedef __attribute__((ext_vector_type(4))) _Float16 f16x4;
typedef __attribute__((ext_vector_type(2))) __fp16 hf16x2;   // cvt_pkrtz return type

union hf2pair {                       // bit-reinterpret 2x(__fp16 x2) -> f16x4
    hf16x2 h[2];
    f16x4  v;
};

// workspace layout (bytes) — R6 layout + PRE (bf16 pre-BN intermediate)
#define OFF_XT 0u               // 2*2304*512*2 = 4,718,592
#define OFF_WQ 4718592u         // 384*512*2    =   393,216
#define OFF_WO 5111808u         // 512*128*2    =   131,072
#define OFF_Q  5242880u         // 2*8*2304*16*2 = 1,179,648
#define OFF_K  6422528u
#define OFF_VT 7602176u
#define OFF_AO 8781824u         // 2*2304*128*2 = 1,179,648 -> 9,961,472
#define OFF_PRE 9961472u        // 2*512*2304*2 = 4,718,592 -> 14,680,064

// ---------------------------------------------------------------------------
// Kernel 0: convert x [b,c,n] fp32 -> xT [b,n,c] bf16 (LDS tile transpose),
//           plus straight fp32->bf16 conversion of w_qkv and w_out.
// (Verified R6. R7/R8 proved fusing this into k1 loses: k1 needs the bf16
// b128 A-path and a >=400-block grid.)
// ---------------------------------------------------------------------------
__global__ __launch_bounds__(256) void k0_convert(
    const float* __restrict__ x, const float* __restrict__ wqkv,
    const float* __restrict__ wout,
    __bf16* __restrict__ xT, __bf16* __restrict__ wqb, __bf16* __restrict__ wob)
{
    int bid = blockIdx.x;
    int t = threadIdx.x;
    if (bid < 576) {
        __shared__ float tile[64][65];
        int b = bid / 288, rem = bid % 288;
        int nt = rem / 8, cb = rem % 8;
        int n0 = nt * 64, c0 = cb * 64;
        int tc = t >> 6, tn = t & 63;
#pragma unroll
        for (int i = 0; i < 16; i++) {
            int cl = i * 4 + tc;
            tile[cl][tn] = x[(size_t)(b * CC + c0 + cl) * NN + n0 + tn];
        }
        __syncthreads();
#pragma unroll
        for (int i = 0; i < 16; i++) {
            int nl = i * 4 + tc;
            xT[(size_t)(b * NN + n0 + nl) * CC + c0 + tn] = (__bf16)tile[tn][nl];
        }
    } else {
        int wid = bid - 576;
        int base = wid * 256 + t;
#pragma unroll
        for (int i = 0; i < 16; i++) {
            int j = base + i * 16384;           // covers 262144 = 384*512 + 512*128
            if (j < O3 * CC) wqb[j] = (__bf16)wqkv[j];
            else             wob[j - O3 * CC] = (__bf16)wout[j - O3 * CC];
        }
    }
}

// ---------------------------------------------------------------------------
// Kernel 1: QKV GEMM  qkvT[n,o] = sum_c xT[n,c] * W[o,c]  (per batch),
//           fused per-head L2 norm of q,k.  ob=6 (64 o-ch/block, 4 acc/wave).
// (Verified R6.)  Outputs: Q,K: [bh][n][16] f16 ;  VT: [bh][16][n] f16
// ---------------------------------------------------------------------------
__global__ __launch_bounds__(256) void k1_qkv(
    const __bf16* __restrict__ xT, const __bf16* __restrict__ wqb,
    _Float16* __restrict__ Q, _Float16* __restrict__ K, _Float16* __restrict__ VT)
{
    int ob = blockIdx.x, nt = blockIdx.y, b = blockIdx.z;
    int lane = threadIdx.x & 63, wave = threadIdx.x >> 6;
    int quad = lane >> 4, col = lane & 15;
    int n0 = nt * 64 + wave * 16;
    int o0 = ob * 64;

    f32x4 acc0 = {0.f,0.f,0.f,0.f}, acc1 = {0.f,0.f,0.f,0.f};
    f32x4 acc2 = {0.f,0.f,0.f,0.f}, acc3 = {0.f,0.f,0.f,0.f};

    const __bf16* arow  = xT + (size_t)(b * NN + n0 + col) * CC + quad * 8;
    const __bf16* brow0 = wqb + (size_t)(o0 + col) * CC + quad * 8;
    const __bf16* brow1 = brow0 + 16 * CC;
    const __bf16* brow2 = brow0 + 32 * CC;
    const __bf16* brow3 = brow0 + 48 * CC;

    bf16x8 a  = *(const bf16x8*)(arow);
    bf16x8 w0 = *(const bf16x8*)(brow0);
    bf16x8 w1 = *(const bf16x8*)(brow1);
    bf16x8 w2 = *(const bf16x8*)(brow2);
    bf16x8 w3 = *(const bf16x8*)(brow3);
#pragma unroll
    for (int ks = 0; ks < 16; ks++) {
        bf16x8 an, wn0, wn1, wn2, wn3;
        if (ks < 15) {
            an  = *(const bf16x8*)(arow + (ks + 1) * 32);
            wn0 = *(const bf16x8*)(brow0 + (ks + 1) * 32);
            wn1 = *(const bf16x8*)(brow1 + (ks + 1) * 32);
            wn2 = *(const bf16x8*)(brow2 + (ks + 1) * 32);
            wn3 = *(const bf16x8*)(brow3 + (ks + 1) * 32);
        }
        acc0 = __builtin_amdgcn_mfma_f32_16x16x32_bf16(a, w0, acc0, 0, 0, 0);
        acc1 = __builtin_amdgcn_mfma_f32_16x16x32_bf16(a, w1, acc1, 0, 0, 0);
        acc2 = __builtin_amdgcn_mfma_f32_16x16x32_bf16(a, w2, acc2, 0, 0, 0);
        acc3 = __builtin_amdgcn_mfma_f32_16x16x32_bf16(a, w3, acc3, 0, 0, 0);
        a = an; w0 = wn0; w1 = wn1; w2 = wn2; w3 = wn3;
    }

#pragma unroll
    for (int s = 0; s < 4; s++) {
        int oc = o0 + s * 16 + col;
        int d = oc & 15, h = (oc >> 4) & 7, kind = oc >> 7;  // 0=q 1=k 2=v
        f32x4 v = (s == 0) ? acc0 : (s == 1) ? acc1 : (s == 2) ? acc2 : acc3;
        if (kind < 2) {
            float ss0 = v[0] * v[0], ss1 = v[1] * v[1], ss2 = v[2] * v[2], ss3 = v[3] * v[3];
#pragma unroll
            for (int m = 1; m < 16; m <<= 1) {
                ss0 += __shfl_xor(ss0, m);
                ss1 += __shfl_xor(ss1, m);
                ss2 += __shfl_xor(ss2, m);
                ss3 += __shfl_xor(ss3, m);
            }
            v[0] *= 1.0f / fmaxf(sqrtf(ss0), 1e-12f);
            v[1] *= 1.0f / fmaxf(sqrtf(ss1), 1e-12f);
            v[2] *= 1.0f / fmaxf(sqrtf(ss2), 1e-12f);
            v[3] *= 1.0f / fmaxf(sqrtf(ss3), 1e-12f);
            _Float16* dst = (kind == 0 ? Q : K) + (size_t)(b * NH + h) * NN * DD;
#pragma unroll
            for (int r = 0; r < 4; r++) {
                int n = n0 + quad * 4 + r;
                dst[(size_t)n * DD + d] = (_Float16)v[r];
            }
        } else {
            f16x4 pk;
#pragma unroll
            for (int r = 0; r < 4; r++) pk[r] = (_Float16)v[r];
            int n = n0 + quad * 4;
            *(f16x4*)(VT + (size_t)((b * NH + h) * DD + d) * NN + n) = pk;
        }
    }
}

// ---------------------------------------------------------------------------
// Kernel 2: attention — transpose-free flash, 8 waves x 288 keys, LDS combine.
// (Verified R6.) temperature*log2e folded into Q frags; packed v_cvt_pkrtz
// for P f32->f16; l-sum via ones-A-fragment MFMA.
// Output: AO[b][n][t=h*16+d] bf16.
// ---------------------------------------------------------------------------
__global__ __launch_bounds__(512) void k2_attn(
    const _Float16* __restrict__ Q, const _Float16* __restrict__ K,
    const _Float16* __restrict__ VT, const float* __restrict__ temp,
    __bf16* __restrict__ AO)
{
    __shared__ float Osh[8][16][64];   // [wave][d][q]
    __shared__ float Lsh[8][64];       // [wave][q]

    int qt = blockIdx.x, bh = blockIdx.y;
    int lane = threadIdx.x & 63, wave = threadIdx.x >> 6;
    int quad = lane >> 4, col = lane & 15;
    int kbase = wave * 288;               // 8 waves x 288 keys = full 2304
    int qbase = qt * 64;

    const _Float16* Qb = Q + (size_t)bh * NN * DD;
    float tl2 = temp[bh & 7] * 1.4426950408889634f;   // exp(x)=2^(x*log2e)
    _Float16 tl2h = (_Float16)tl2;

    f16x4 qf0 = *(const f16x4*)(Qb + (size_t)(qbase +  0 + col) * DD + quad * 4);
    f16x4 qf1 = *(const f16x4*)(Qb + (size_t)(qbase + 16 + col) * DD + quad * 4);
    f16x4 qf2 = *(const f16x4*)(Qb + (size_t)(qbase + 32 + col) * DD + quad * 4);
    f16x4 qf3 = *(const f16x4*)(Qb + (size_t)(qbase + 48 + col) * DD + quad * 4);
#pragma unroll
    for (int j = 0; j < 4; j++) {      // fold temperature*log2e into Q
        qf0[j] *= tl2h; qf1[j] *= tl2h; qf2[j] *= tl2h; qf3[j] *= tl2h;
    }
    const f16x4 onesf = {(_Float16)1.f, (_Float16)1.f, (_Float16)1.f, (_Float16)1.f};

    f32x4 oa0 = {0.f,0.f,0.f,0.f}, oa1 = {0.f,0.f,0.f,0.f};
    f32x4 oa2 = {0.f,0.f,0.f,0.f}, oa3 = {0.f,0.f,0.f,0.f};
    f32x4 lc0 = {0.f,0.f,0.f,0.f}, lc1 = {0.f,0.f,0.f,0.f};
    f32x4 lc2 = {0.f,0.f,0.f,0.f}, lc3 = {0.f,0.f,0.f,0.f};
    const f32x4 zc = {0.f,0.f,0.f,0.f};

    const _Float16* kp = K + (size_t)bh * NN * DD + (size_t)(kbase + col) * DD + quad * 4;
    const _Float16* vp = VT + (size_t)bh * DD * NN + (size_t)col * NN + kbase + quad * 4;

    f16x4 kfa = *(const f16x4*)(kp);
    f16x4 kfb = *(const f16x4*)(kp + 16 * DD);
    f16x4 vfa = *(const f16x4*)(vp);
    f16x4 vfb = *(const f16x4*)(vp + 16);

#define K2_CHUNK(KF, VF)                                                        \
    {                                                                           \
        f32x4 s0 = __builtin_amdgcn_mfma_f32_16x16x16f16(KF, qf0, zc, 0, 0, 0); \
        f32x4 s1 = __builtin_amdgcn_mfma_f32_16x16x16f16(KF, qf1, zc, 0, 0, 0); \
        f32x4 s2 = __builtin_amdgcn_mfma_f32_16x16x16f16(KF, qf2, zc, 0, 0, 0); \
        f32x4 s3 = __builtin_amdgcn_mfma_f32_16x16x16f16(KF, qf3, zc, 0, 0, 0); \
        hf2pair u0, u1, u2, u3;                                                 \
        u0.h[0] = __builtin_amdgcn_cvt_pkrtz(__builtin_amdgcn_exp2f(s0[0]),     \
                                             __builtin_amdgcn_exp2f(s0[1]));    \
        u0.h[1] = __builtin_amdgcn_cvt_pkrtz(__builtin_amdgcn_exp2f(s0[2]),     \
                                             __builtin_amdgcn_exp2f(s0[3]));    \
        u1.h[0] = __builtin_amdgcn_cvt_pkrtz(__builtin_amdgcn_exp2f(s1[0]),     \
                                             __builtin_amdgcn_exp2f(s1[1]));    \
        u1.h[1] = __builtin_amdgcn_cvt_pkrtz(__builtin_amdgcn_exp2f(s1[2]),     \
                                             __builtin_amdgcn_exp2f(s1[3]));    \
        u2.h[0] = __builtin_amdgcn_cvt_pkrtz(__builtin_amdgcn_exp2f(s2[0]),     \
                                             __builtin_amdgcn_exp2f(s2[1]));    \
        u2.h[1] = __builtin_amdgcn_cvt_pkrtz(__builtin_amdgcn_exp2f(s2[2]),     \
                                             __builtin_amdgcn_exp2f(s2[3]));    \
        u3.h[0] = __builtin_amdgcn_cvt_pkrtz(__builtin_amdgcn_exp2f(s3[0]),     \
                                             __builtin_amdgcn_exp2f(s3[1]));    \
        u3.h[1] = __builtin_amdgcn_cvt_pkrtz(__builtin_amdgcn_exp2f(s3[2]),     \
                                             __builtin_amdgcn_exp2f(s3[3]));    \
        f16x4 p0 = u0.v, p1 = u1.v, p2 = u2.v, p3 = u3.v;                       \
        lc0 = __builtin_amdgcn_mfma_f32_16x16x16f16(onesf, p0, lc0, 0, 0, 0);   \
        lc1 = __builtin_amdgcn_mfma_f32_16x16x16f16(onesf, p1, lc1, 0, 0, 0);   \
        lc2 = __builtin_amdgcn_mfma_f32_16x16x16f16(onesf, p2, lc2, 0, 0, 0);   \
        lc3 = __builtin_amdgcn_mfma_f32_16x16x16f16(onesf, p3, lc3, 0, 0, 0);   \
        oa0 = __builtin_amdgcn_mfma_f32_16x16x16f16(VF, p0, oa0, 0, 0, 0);      \
        oa1 = __builtin_amdgcn_mfma_f32_16x16x16f16(VF, p1, oa1, 0, 0, 0);      \
        oa2 = __builtin_amdgcn_mfma_f32_16x16x16f16(VF, p2, oa2, 0, 0, 0);      \
        oa3 = __builtin_amdgcn_mfma_f32_16x16x16f16(VF, p3, oa3, 0, 0, 0);      \
    }

    for (int g = 0; g < 9; ++g) {        // 9 groups x 32 keys = 288
        f16x4 kna, knb, vna, vnb;
        if (g < 8) {
            kna = *(const f16x4*)(kp + 32 * DD);
            knb = *(const f16x4*)(kp + 48 * DD);
            vna = *(const f16x4*)(vp + 32);
            vnb = *(const f16x4*)(vp + 48);
        }
        K2_CHUNK(kfa, vfa)
        K2_CHUNK(kfb, vfb)
        kfa = kna; kfb = knb; vfa = vna; vfb = vnb;
        kp += 32 * DD; vp += 32;
    }
#undef K2_CHUNK

    // lc rows are all identical = l[q=col] partial over this wave's keys.
#pragma unroll
    for (int r = 0; r < 4; ++r) {
        Osh[wave][quad * 4 + r][ 0 + col] = oa0[r];
        Osh[wave][quad * 4 + r][16 + col] = oa1[r];
        Osh[wave][quad * 4 + r][32 + col] = oa2[r];
        Osh[wave][quad * 4 + r][48 + col] = oa3[r];
    }
    float lv = (quad == 0) ? lc0[0] : (quad == 1) ? lc1[0] : (quad == 2) ? lc2[0] : lc3[0];
    Lsh[wave][quad * 16 + col] = lv;
    __syncthreads();

    int t = threadIdx.x;
    int q = t & 63, dg = t >> 6;          // dg in 0..7 -> d = dg*2, dg*2+1
    float l = 0.f;
#pragma unroll
    for (int w = 0; w < 8; ++w) l += Lsh[w][q];
    float inv = 1.0f / l;
    float o0 = 0.f, o1 = 0.f;
#pragma unroll
    for (int w = 0; w < 8; ++w) {
        o0 += Osh[w][dg * 2 + 0][q];
        o1 += Osh[w][dg * 2 + 1][q];
    }
    int b = bh >> 3, h = bh & 7;
    __bf16* dst = AO + (size_t)(b * NN + qbase + q) * TT + h * DD + dg * 2;
    dst[0] = (__bf16)(o0 * inv);
    dst[1] = (__bf16)(o1 * inv);
}

// ---------------------------------------------------------------------------
// Kernel 3: projection  pre[b,c,n] = sum_t w_out[c,t] * AO[b,n,t].
// R9: writes bf16 intermediate (halves k3-store + k4-load HBM traffic; BN
// stats are computed on bf16-rounded values, added err ~0.2% rel, within
// threshold margin 0.089 vs current 0.031).
// ---------------------------------------------------------------------------
__global__ __launch_bounds__(256) void k3_proj(
    const __bf16* __restrict__ AO, const __bf16* __restrict__ wob,
    __bf16* __restrict__ pre)
{
    int cb = blockIdx.x, nt = blockIdx.y, b = blockIdx.z;
    int lane = threadIdx.x & 63, wave = threadIdx.x >> 6;
    int quad = lane >> 4, col = lane & 15;
    int n0 = nt * 64 + wave * 16, c0 = cb * 32;

    f32x4 acc0 = {0.f, 0.f, 0.f, 0.f};
    f32x4 acc1 = {0.f, 0.f, 0.f, 0.f};

    const __bf16* ab = AO + (size_t)(b * NN + n0 + col) * TT + quad * 8;
    const __bf16* wb0 = wob + (size_t)(c0 + col) * TT + quad * 8;
    const __bf16* wb1 = wb0 + 16 * TT;
#pragma unroll
    for (int ks = 0; ks < 4; ks++) {
        bf16x8 a  = *(const bf16x8*)(ab + ks * 32);
        bf16x8 w0 = *(const bf16x8*)(wb0 + ks * 32);
        bf16x8 w1 = *(const bf16x8*)(wb1 + ks * 32);
        acc0 = __builtin_amdgcn_mfma_f32_16x16x32_bf16(a, w0, acc0, 0, 0, 0);
        acc1 = __builtin_amdgcn_mfma_f32_16x16x32_bf16(a, w1, acc1, 0, 0, 0);
    }
#pragma unroll
    for (int s = 0; s < 2; s++) {
        int c = c0 + s * 16 + col;
        f32x4 v = (s == 0) ? acc0 : acc1;
        bf16x4 pk;
        pk[0] = (__bf16)v[0]; pk[1] = (__bf16)v[1];
        pk[2] = (__bf16)v[2]; pk[3] = (__bf16)v[3];
        *(bf16x4*)(pre + (size_t)(b * CC + c) * NN + n0 + quad * 4) = pk;
    }
}

// ---------------------------------------------------------------------------
// Kernel 4: training-mode BatchNorm. Reads bf16 pre, writes fp32 out.
// One block per channel.
// ---------------------------------------------------------------------------
__global__ __launch_bounds__(256) void k4_bn(
    const __bf16* __restrict__ pre, float* __restrict__ out,
    const float* __restrict__ gamma, const float* __restrict__ beta)
{
    int c = blockIdx.x;
    int t = threadIdx.x;
    float vals[18];
    float s = 0.f, q = 0.f;
#pragma unroll
    for (int i = 0; i < 18; i++) {
        int j = i * 256 + t;          // 0..4607 over (b,n)
        int b = j / NN, n = j % NN;
        float v = (float)pre[(size_t)(b * CC + c) * NN + n];
        vals[i] = v; s += v; q += v * v;
    }
#pragma unroll
    for (int m = 1; m < 64; m <<= 1) { s += __shfl_xor(s, m); q += __shfl_xor(q, m); }
    __shared__ float rs[4], rq[4];
    int lane = t & 63, wave = t >> 6;
    if (lane == 0) { rs[wave] = s; rq[wave] = q; }
    __syncthreads();
    s = rs[0] + rs[1] + rs[2] + rs[3];
    q = rq[0] + rq[1] + rq[2] + rq[3];
    float mean = s * (1.0f / 4608.0f);
    float var = q * (1.0f / 4608.0f) - mean * mean;
    float sc = rsqrtf(var + 1e-5f) * gamma[c];
    float sh = beta[c] - mean * sc;
#pragma unroll
    for (int i = 0; i < 18; i++) {
        int j = i * 256 + t;
        int b = j / NN, n = j % NN;
        out[(size_t)(b * CC + c) * NN + n] = vals[i] * sc + sh;
    }
}

// ---------------------------------------------------------------------------
extern "C" void kernel_launch(void* const* d_in, const int* in_sizes, int n_in,
                              void* d_out, int out_size, void* d_ws, size_t ws_size,
                              hipStream_t stream) {
    const float* x     = (const float*)d_in[0];
    const float* wqkv  = (const float*)d_in[1];
    const float* temp  = (const float*)d_in[2];
    const float* wout  = (const float*)d_in[3];
    const float* gamma = (const float*)d_in[4];
    const float* beta  = (const float*)d_in[5];
    float* out = (float*)d_out;
    char* ws = (char*)d_ws;

    __bf16* xT  = (__bf16*)(ws + OFF_XT);
    __bf16* wqb = (__bf16*)(ws + OFF_WQ);
    __bf16* wob = (__bf16*)(ws + OFF_WO);
    _Float16* Q  = (_Float16*)(ws + OFF_Q);
    _Float16* K  = (_Float16*)(ws + OFF_K);
    _Float16* VT = (_Float16*)(ws + OFF_VT);
    __bf16* AO  = (__bf16*)(ws + OFF_AO);
    __bf16* PRE = (__bf16*)(ws + OFF_PRE);

    k0_convert<<<640, 256, 0, stream>>>(x, wqkv, wout, xT, wqb, wob);
    k1_qkv<<<dim3(6, 36, 2), 256, 0, stream>>>(xT, wqb, Q, K, VT);
    k2_attn<<<dim3(36, 16), 512, 0, stream>>>(Q, K, VT, temp, AO);
    k3_proj<<<dim3(16, 36, 2), 256, 0, stream>>>(AO, wob, PRE);
    k4_bn<<<512, 256, 0, stream>>>(PRE, out, gamma, beta);
}

// Round 10
// 127.181 us; speedup vs baseline: 1.3717x; 1.0337x over previous
//
#include <hip/hip_runtime.h>

// Problem constants
#define NB 2
#define CC 512
#define NN 2304
#define NH 8
#define DD 16
#define TT 128          // NH*DD
#define O3 384          // 3*TT

typedef __attribute__((ext_vector_type(4))) float f32x4;
typedef __attribute__((ext_vector_type(8))) __bf16 bf16x8;
typedef __attribute__((ext_vector_type(4))) __bf16 bf16x4;
typedef __attribute__((ext_vector_type(2))) __bf16 bf16x2;
typedef __attribute__((ext_vector_type(4))) _Float16 f16x4;
typedef __attribute__((ext_vector_type(2))) __fp16 hf16x2;   // cvt_pkrtz return type

union hf2pair {                       // bit-reinterpret 2x(__fp16 x2) -> f16x4
    hf16x2 h[2];
    f16x4  v;
};

// workspace layout (bytes)
#define OFF_XT 0u               // 2*2304*512*2 = 4,718,592
#define OFF_WQ 4718592u         // 384*512*2    =   393,216
#define OFF_WO 5111808u         // 512*128*2    =   131,072
#define OFF_Q  5242880u         // 2*8*2304*16*2 = 1,179,648
#define OFF_K  6422528u
#define OFF_VT 7602176u
#define OFF_AO 8781824u         // 2*2304*128*2 = 1,179,648 -> 9,961,472
#define OFF_PRE 9961472u        // 2*512*2304*2 = 4,718,592 -> 14,680,064

// ---------------------------------------------------------------------------
// Kernel 0: convert x [b,c,n] fp32 -> xT [b,n,c] bf16 (LDS tile transpose),
//           plus fp32->bf16 conversion of w_qkv and w_out.
// R10: vectorized — f32x4 x-reads (4 iters), bf16x4 xT-writes (4 iters, 8B/
// lane vs old 2B/lane), f32x4->bf16x4 weight conversion (4 iters).
// ---------------------------------------------------------------------------
__global__ __launch_bounds__(256) void k0_convert(
    const float* __restrict__ x, const float* __restrict__ wqkv,
    const float* __restrict__ wout,
    __bf16* __restrict__ xT, __bf16* __restrict__ wqb, __bf16* __restrict__ wob)
{
    int bid = blockIdx.x;
    int t = threadIdx.x;
    if (bid < 576) {
        __shared__ float tile[64][65];
        int b = bid / 288, rem = bid % 288;
        int nt = rem / 8, cb = rem % 8;
        int n0 = nt * 64, c0 = cb * 64;
        int nq = (t & 15) * 4;          // n quad within tile
        int cs = t >> 4;                // 0..15
#pragma unroll
        for (int i = 0; i < 4; i++) {
            int c = i * 16 + cs;
            f32x4 v = *(const f32x4*)(x + (size_t)(b * CC + c0 + c) * NN + n0 + nq);
            tile[c][nq + 0] = v[0];
            tile[c][nq + 1] = v[1];
            tile[c][nq + 2] = v[2];
            tile[c][nq + 3] = v[3];
        }
        __syncthreads();
        int cq = (t & 15) * 4;          // c quad for write phase
        int ns = t >> 4;                // 0..15
#pragma unroll
        for (int i = 0; i < 4; i++) {
            int n = i * 16 + ns;
            bf16x4 pk;
            pk[0] = (__bf16)tile[cq + 0][n];
            pk[1] = (__bf16)tile[cq + 1][n];
            pk[2] = (__bf16)tile[cq + 2][n];
            pk[3] = (__bf16)tile[cq + 3][n];
            *(bf16x4*)(xT + (size_t)(b * NN + n0 + n) * CC + c0 + cq) = pk;
        }
    } else {
        int wid = bid - 576;
#pragma unroll
        for (int i = 0; i < 4; i++) {
            int jq = wid * 256 + t + i * 16384;   // quad index; 64 blk x 256 x 4 = 65536
            int j = jq * 4;                        // element index (quads never straddle)
            f32x4 v = (j < O3 * CC) ? *(const f32x4*)(wqkv + j)
                                    : *(const f32x4*)(wout + (j - O3 * CC));
            bf16x4 pk;
            pk[0] = (__bf16)v[0]; pk[1] = (__bf16)v[1];
            pk[2] = (__bf16)v[2]; pk[3] = (__bf16)v[3];
            if (j < O3 * CC) *(bf16x4*)(wqb + j) = pk;
            else             *(bf16x4*)(wob + (j - O3 * CC)) = pk;
        }
    }
}

// ---------------------------------------------------------------------------
// Kernel 1: QKV GEMM  qkvT[n,o] = sum_c xT[n,c] * W[o,c]  (per batch),
//           fused per-head L2 norm of q,k.  ob=6 (64 o-ch/block, 4 acc/wave).
// (Verified R6/R9.)  Outputs: Q,K: [bh][n][16] f16 ;  VT: [bh][16][n] f16
// ---------------------------------------------------------------------------
__global__ __launch_bounds__(256) void k1_qkv(
    const __bf16* __restrict__ xT, const __bf16* __restrict__ wqb,
    _Float16* __restrict__ Q, _Float16* __restrict__ K, _Float16* __restrict__ VT)
{
    int ob = blockIdx.x, nt = blockIdx.y, b = blockIdx.z;
    int lane = threadIdx.x & 63, wave = threadIdx.x >> 6;
    int quad = lane >> 4, col = lane & 15;
    int n0 = nt * 64 + wave * 16;
    int o0 = ob * 64;

    f32x4 acc0 = {0.f,0.f,0.f,0.f}, acc1 = {0.f,0.f,0.f,0.f};
    f32x4 acc2 = {0.f,0.f,0.f,0.f}, acc3 = {0.f,0.f,0.f,0.f};

    const __bf16* arow  = xT + (size_t)(b * NN + n0 + col) * CC + quad * 8;
    const __bf16* brow0 = wqb + (size_t)(o0 + col) * CC + quad * 8;
    const __bf16* brow1 = brow0 + 16 * CC;
    const __bf16* brow2 = brow0 + 32 * CC;
    const __bf16* brow3 = brow0 + 48 * CC;

    bf16x8 a  = *(const bf16x8*)(arow);
    bf16x8 w0 = *(const bf16x8*)(brow0);
    bf16x8 w1 = *(const bf16x8*)(brow1);
    bf16x8 w2 = *(const bf16x8*)(brow2);
    bf16x8 w3 = *(const bf16x8*)(brow3);
#pragma unroll
    for (int ks = 0; ks < 16; ks++) {
        bf16x8 an, wn0, wn1, wn2, wn3;
        if (ks < 15) {
            an  = *(const bf16x8*)(arow + (ks + 1) * 32);
            wn0 = *(const bf16x8*)(brow0 + (ks + 1) * 32);
            wn1 = *(const bf16x8*)(brow1 + (ks + 1) * 32);
            wn2 = *(const bf16x8*)(brow2 + (ks + 1) * 32);
            wn3 = *(const bf16x8*)(brow3 + (ks + 1) * 32);
        }
        acc0 = __builtin_amdgcn_mfma_f32_16x16x32_bf16(a, w0, acc0, 0, 0, 0);
        acc1 = __builtin_amdgcn_mfma_f32_16x16x32_bf16(a, w1, acc1, 0, 0, 0);
        acc2 = __builtin_amdgcn_mfma_f32_16x16x32_bf16(a, w2, acc2, 0, 0, 0);
        acc3 = __builtin_amdgcn_mfma_f32_16x16x32_bf16(a, w3, acc3, 0, 0, 0);
        a = an; w0 = wn0; w1 = wn1; w2 = wn2; w3 = wn3;
    }

#pragma unroll
    for (int s = 0; s < 4; s++) {
        int oc = o0 + s * 16 + col;
        int d = oc & 15, h = (oc >> 4) & 7, kind = oc >> 7;  // 0=q 1=k 2=v
        f32x4 v = (s == 0) ? acc0 : (s == 1) ? acc1 : (s == 2) ? acc2 : acc3;
        if (kind < 2) {
            float ss0 = v[0] * v[0], ss1 = v[1] * v[1], ss2 = v[2] * v[2], ss3 = v[3] * v[3];
#pragma unroll
            for (int m = 1; m < 16; m <<= 1) {
                ss0 += __shfl_xor(ss0, m);
                ss1 += __shfl_xor(ss1, m);
                ss2 += __shfl_xor(ss2, m);
                ss3 += __shfl_xor(ss3, m);
            }
            v[0] *= 1.0f / fmaxf(sqrtf(ss0), 1e-12f);
            v[1] *= 1.0f / fmaxf(sqrtf(ss1), 1e-12f);
            v[2] *= 1.0f / fmaxf(sqrtf(ss2), 1e-12f);
            v[3] *= 1.0f / fmaxf(sqrtf(ss3), 1e-12f);
            _Float16* dst = (kind == 0 ? Q : K) + (size_t)(b * NH + h) * NN * DD;
#pragma unroll
            for (int r = 0; r < 4; r++) {
                int n = n0 + quad * 4 + r;
                dst[(size_t)n * DD + d] = (_Float16)v[r];
            }
        } else {
            f16x4 pk;
#pragma unroll
            for (int r = 0; r < 4; r++) pk[r] = (_Float16)v[r];
            int n = n0 + quad * 4;
            *(f16x4*)(VT + (size_t)((b * NH + h) * DD + d) * NN + n) = pk;
        }
    }
}

// ---------------------------------------------------------------------------
// Kernel 2: attention — transpose-free flash, 8 waves x 288 keys, LDS combine.
// R10: l-sum moved BACK to f32 VALU accumulation (R1-verified semantics) —
// drops the 4 ones-MFMAs/chunk (12 -> 8 MFMA, -33%); the 16 v_add hide under
// the trans pipe (exp2 is the per-wave bottleneck at ~128cyc/chunk).
// temperature*log2e stays folded into Q; cvt_pkrtz packing kept; AO store
// packed to one bf16x2.
// Output: AO[b][n][t=h*16+d] bf16.
// ---------------------------------------------------------------------------
__global__ __launch_bounds__(512) void k2_attn(
    const _Float16* __restrict__ Q, const _Float16* __restrict__ K,
    const _Float16* __restrict__ VT, const float* __restrict__ temp,
    __bf16* __restrict__ AO)
{
    __shared__ float Osh[8][16][64];   // [wave][d][q]
    __shared__ float Lsh[8][64];       // [wave][q]

    int qt = blockIdx.x, bh = blockIdx.y;
    int lane = threadIdx.x & 63, wave = threadIdx.x >> 6;
    int quad = lane >> 4, col = lane & 15;
    int kbase = wave * 288;               // 8 waves x 288 keys = full 2304
    int qbase = qt * 64;

    const _Float16* Qb = Q + (size_t)bh * NN * DD;
    float tl2 = temp[bh & 7] * 1.4426950408889634f;   // exp(x)=2^(x*log2e)
    _Float16 tl2h = (_Float16)tl2;

    f16x4 qf0 = *(const f16x4*)(Qb + (size_t)(qbase +  0 + col) * DD + quad * 4);
    f16x4 qf1 = *(const f16x4*)(Qb + (size_t)(qbase + 16 + col) * DD + quad * 4);
    f16x4 qf2 = *(const f16x4*)(Qb + (size_t)(qbase + 32 + col) * DD + quad * 4);
    f16x4 qf3 = *(const f16x4*)(Qb + (size_t)(qbase + 48 + col) * DD + quad * 4);
#pragma unroll
    for (int j = 0; j < 4; j++) {      // fold temperature*log2e into Q
        qf0[j] *= tl2h; qf1[j] *= tl2h; qf2[j] *= tl2h; qf3[j] *= tl2h;
    }

    f32x4 oa0 = {0.f,0.f,0.f,0.f}, oa1 = {0.f,0.f,0.f,0.f};
    f32x4 oa2 = {0.f,0.f,0.f,0.f}, oa3 = {0.f,0.f,0.f,0.f};
    float la0 = 0.f, la1 = 0.f, la2 = 0.f, la3 = 0.f;
    const f32x4 zc = {0.f,0.f,0.f,0.f};

    const _Float16* kp = K + (size_t)bh * NN * DD + (size_t)(kbase + col) * DD + quad * 4;
    const _Float16* vp = VT + (size_t)bh * DD * NN + (size_t)col * NN + kbase + quad * 4;

    f16x4 kfa = *(const f16x4*)(kp);
    f16x4 kfb = *(const f16x4*)(kp + 16 * DD);
    f16x4 vfa = *(const f16x4*)(vp);
    f16x4 vfb = *(const f16x4*)(vp + 16);

#define K2_CHUNK(KF, VF)                                                        \
    {                                                                           \
        f32x4 s0 = __builtin_amdgcn_mfma_f32_16x16x16f16(KF, qf0, zc, 0, 0, 0); \
        f32x4 s1 = __builtin_amdgcn_mfma_f32_16x16x16f16(KF, qf1, zc, 0, 0, 0); \
        f32x4 s2 = __builtin_amdgcn_mfma_f32_16x16x16f16(KF, qf2, zc, 0, 0, 0); \
        f32x4 s3 = __builtin_amdgcn_mfma_f32_16x16x16f16(KF, qf3, zc, 0, 0, 0); \
        float e00 = __builtin_amdgcn_exp2f(s0[0]), e01 = __builtin_amdgcn_exp2f(s0[1]); \
        float e02 = __builtin_amdgcn_exp2f(s0[2]), e03 = __builtin_amdgcn_exp2f(s0[3]); \
        float e10 = __builtin_amdgcn_exp2f(s1[0]), e11 = __builtin_amdgcn_exp2f(s1[1]); \
        float e12 = __builtin_amdgcn_exp2f(s1[2]), e13 = __builtin_amdgcn_exp2f(s1[3]); \
        float e20 = __builtin_amdgcn_exp2f(s2[0]), e21 = __builtin_amdgcn_exp2f(s2[1]); \
        float e22 = __builtin_amdgcn_exp2f(s2[2]), e23 = __builtin_amdgcn_exp2f(s2[3]); \
        float e30 = __builtin_amdgcn_exp2f(s3[0]), e31 = __builtin_amdgcn_exp2f(s3[1]); \
        float e32 = __builtin_amdgcn_exp2f(s3[2]), e33 = __builtin_amdgcn_exp2f(s3[3]); \
        la0 += (e00 + e01) + (e02 + e03);                                       \
        la1 += (e10 + e11) + (e12 + e13);                                       \
        la2 += (e20 + e21) + (e22 + e23);                                       \
        la3 += (e30 + e31) + (e32 + e33);                                       \
        hf2pair u0, u1, u2, u3;                                                 \
        u0.h[0] = __builtin_amdgcn_cvt_pkrtz(e00, e01);                         \
        u0.h[1] = __builtin_amdgcn_cvt_pkrtz(e02, e03);                         \
        u1.h[0] = __builtin_amdgcn_cvt_pkrtz(e10, e11);                         \
        u1.h[1] = __builtin_amdgcn_cvt_pkrtz(e12, e13);                         \
        u2.h[0] = __builtin_amdgcn_cvt_pkrtz(e20, e21);                         \
        u2.h[1] = __builtin_amdgcn_cvt_pkrtz(e22, e23);                         \
        u3.h[0] = __builtin_amdgcn_cvt_pkrtz(e30, e31);                         \
        u3.h[1] = __builtin_amdgcn_cvt_pkrtz(e32, e33);                         \
        oa0 = __builtin_amdgcn_mfma_f32_16x16x16f16(VF, u0.v, oa0, 0, 0, 0);    \
        oa1 = __builtin_amdgcn_mfma_f32_16x16x16f16(VF, u1.v, oa1, 0, 0, 0);    \
        oa2 = __builtin_amdgcn_mfma_f32_16x16x16f16(VF, u2.v, oa2, 0, 0, 0);    \
        oa3 = __builtin_amdgcn_mfma_f32_16x16x16f16(VF, u3.v, oa3, 0, 0, 0);    \
    }

    for (int g = 0; g < 9; ++g) {        // 9 groups x 32 keys = 288
        f16x4 kna, knb, vna, vnb;
        if (g < 8) {
            kna = *(const f16x4*)(kp + 32 * DD);
            knb = *(const f16x4*)(kp + 48 * DD);
            vna = *(const f16x4*)(vp + 32);
            vnb = *(const f16x4*)(vp + 48);
        }
        K2_CHUNK(kfa, vfa)
        K2_CHUNK(kfb, vfb)
        kfa = kna; kfb = knb; vfa = vna; vfb = vnb;
        kp += 32 * DD; vp += 32;
    }
#undef K2_CHUNK

    // reduce l across quads: after this every lane holds l[q=col] per frag
    la0 += __shfl_xor(la0, 16); la0 += __shfl_xor(la0, 32);
    la1 += __shfl_xor(la1, 16); la1 += __shfl_xor(la1, 32);
    la2 += __shfl_xor(la2, 16); la2 += __shfl_xor(la2, 32);
    la3 += __shfl_xor(la3, 16); la3 += __shfl_xor(la3, 32);

#pragma unroll
    for (int r = 0; r < 4; ++r) {
        Osh[wave][quad * 4 + r][ 0 + col] = oa0[r];
        Osh[wave][quad * 4 + r][16 + col] = oa1[r];
        Osh[wave][quad * 4 + r][32 + col] = oa2[r];
        Osh[wave][quad * 4 + r][48 + col] = oa3[r];
    }
    float lv = (quad == 0) ? la0 : (quad == 1) ? la1 : (quad == 2) ? la2 : la3;
    Lsh[wave][quad * 16 + col] = lv;
    __syncthreads();

    int t = threadIdx.x;
    int q = t & 63, dg = t >> 6;          // dg in 0..7 -> d = dg*2, dg*2+1
    float l = 0.f;
#pragma unroll
    for (int w = 0; w < 8; ++w) l += Lsh[w][q];
    float inv = 1.0f / l;
    float o0 = 0.f, o1 = 0.f;
#pragma unroll
    for (int w = 0; w < 8; ++w) {
        o0 += Osh[w][dg * 2 + 0][q];
        o1 += Osh[w][dg * 2 + 1][q];
    }
    int b = bh >> 3, h = bh & 7;
    bf16x2 pk;
    pk[0] = (__bf16)(o0 * inv);
    pk[1] = (__bf16)(o1 * inv);
    *(bf16x2*)(AO + (size_t)(b * NN + qbase + q) * TT + h * DD + dg * 2) = pk;
}

// ---------------------------------------------------------------------------
// Kernel 3: projection  pre[b,c,n] = sum_t w_out[c,t] * AO[b,n,t], bf16 out.
// (Verified R9.)
// ---------------------------------------------------------------------------
__global__ __launch_bounds__(256) void k3_proj(
    const __bf16* __restrict__ AO, const __bf16* __restrict__ wob,
    __bf16* __restrict__ pre)
{
    int cb = blockIdx.x, nt = blockIdx.y, b = blockIdx.z;
    int lane = threadIdx.x & 63, wave = threadIdx.x >> 6;
    int quad = lane >> 4, col = lane & 15;
    int n0 = nt * 64 + wave * 16, c0 = cb * 32;

    f32x4 acc0 = {0.f, 0.f, 0.f, 0.f};
    f32x4 acc1 = {0.f, 0.f, 0.f, 0.f};

    const __bf16* ab = AO + (size_t)(b * NN + n0 + col) * TT + quad * 8;
    const __bf16* wb0 = wob + (size_t)(c0 + col) * TT + quad * 8;
    const __bf16* wb1 = wb0 + 16 * TT;
#pragma unroll
    for (int ks = 0; ks < 4; ks++) {
        bf16x8 a  = *(const bf16x8*)(ab + ks * 32);
        bf16x8 w0 = *(const bf16x8*)(wb0 + ks * 32);
        bf16x8 w1 = *(const bf16x8*)(wb1 + ks * 32);
        acc0 = __builtin_amdgcn_mfma_f32_16x16x32_bf16(a, w0, acc0, 0, 0, 0);
        acc1 = __builtin_amdgcn_mfma_f32_16x16x32_bf16(a, w1, acc1, 0, 0, 0);
    }
#pragma unroll
    for (int s = 0; s < 2; s++) {
        int c = c0 + s * 16 + col;
        f32x4 v = (s == 0) ? acc0 : acc1;
        bf16x4 pk;
        pk[0] = (__bf16)v[0]; pk[1] = (__bf16)v[1];
        pk[2] = (__bf16)v[2]; pk[3] = (__bf16)v[3];
        *(bf16x4*)(pre + (size_t)(b * CC + c) * NN + n0 + quad * 4) = pk;
    }
}

// ---------------------------------------------------------------------------
// Kernel 4: training-mode BatchNorm. Reads bf16 pre, writes fp32 out.
// R10: fully vectorized — per b: 2x bf16x4 loads + 1 scalar tail (vs 9
// scalar bf16 loads), f32x4 stores. One block per channel.
// ---------------------------------------------------------------------------
__global__ __launch_bounds__(256) void k4_bn(
    const __bf16* __restrict__ pre, float* __restrict__ out,
    const float* __restrict__ gamma, const float* __restrict__ beta)
{
    int c = blockIdx.x;
    int t = threadIdx.x;
    float vals[2][9];
    float s = 0.f, q = 0.f;
#pragma unroll
    for (int b = 0; b < 2; b++) {
        const __bf16* base = pre + (size_t)(b * CC + c) * NN;
#pragma unroll
        for (int r = 0; r < 2; r++) {
            bf16x4 x4 = *(const bf16x4*)(base + r * 1024 + t * 4);
#pragma unroll
            for (int j = 0; j < 4; j++) {
                float v = (float)x4[j];
                vals[b][r * 4 + j] = v; s += v; q += v * v;
            }
        }
        float v = (float)base[2048 + t];
        vals[b][8] = v; s += v; q += v * v;
    }
#pragma unroll
    for (int m = 1; m < 64; m <<= 1) { s += __shfl_xor(s, m); q += __shfl_xor(q, m); }
    __shared__ float rs[4], rq[4];
    int lane = t & 63, wave = t >> 6;
    if (lane == 0) { rs[wave] = s; rq[wave] = q; }
    __syncthreads();
    s = rs[0] + rs[1] + rs[2] + rs[3];
    q = rq[0] + rq[1] + rq[2] + rq[3];
    float mean = s * (1.0f / 4608.0f);
    float var = q * (1.0f / 4608.0f) - mean * mean;
    float sc = rsqrtf(var + 1e-5f) * gamma[c];
    float sh = beta[c] - mean * sc;
#pragma unroll
    for (int b = 0; b < 2; b++) {
        float* obase = out + (size_t)(b * CC + c) * NN;
#pragma unroll
        for (int r = 0; r < 2; r++) {
            f32x4 o;
#pragma unroll
            for (int j = 0; j < 4; j++) o[j] = vals[b][r * 4 + j] * sc + sh;
            *(f32x4*)(obase + r * 1024 + t * 4) = o;
        }
        obase[2048 + t] = vals[b][8] * sc + sh;
    }
}

// ---------------------------------------------------------------------------
extern "C" void kernel_launch(void* const* d_in, const int* in_sizes, int n_in,
                              void* d_out, int out_size, void* d_ws, size_t ws_size,
                              hipStream_t stream) {
    const float* x     = (const float*)d_in[0];
    const float* wqkv  = (const float*)d_in[1];
    const float* temp  = (const float*)d_in[2];
    const float* wout  = (const float*)d_in[3];
    const float* gamma = (const float*)d_in[4];
    const float* beta  = (const float*)d_in[5];
    float* out = (float*)d_out;
    char* ws = (char*)d_ws;

    __bf16* xT  = (__bf16*)(ws + OFF_XT);
    __bf16* wqb = (__bf16*)(ws + OFF_WQ);
    __bf16* wob = (__bf16*)(ws + OFF_WO);
    _Float16* Q  = (_Float16*)(ws + OFF_Q);
    _Float16* K  = (_Float16*)(ws + OFF_K);
    _Float16* VT = (_Float16*)(ws + OFF_VT);
    __bf16* AO  = (__bf16*)(ws + OFF_AO);
    __bf16* PRE = (__bf16*)(ws + OFF_PRE);

    k0_convert<<<640, 256, 0, stream>>>(x, wqkv, wout, xT, wqb, wob);
    k1_qkv<<<dim3(6, 36, 2), 256, 0, stream>>>(xT, wqb, Q, K, VT);
    k2_attn<<<dim3(36, 16), 512, 0, stream>>>(Q, K, VT, temp, AO);
    k3_proj<<<dim3(16, 36, 2), 256, 0, stream>>>(AO, wob, PRE);
    k4_bn<<<512, 256, 0, stream>>>(PRE, out, gamma, beta);
}